// Round 13
// baseline (506.647 us; speedup 1.0000x reference)
//
#include <hip/hip_runtime.h>

typedef unsigned short u16;
typedef __attribute__((ext_vector_type(8))) short bf16x8;
typedef __attribute__((ext_vector_type(4))) float f32x4;

#define CSR_CHUNK 12288   // edges per block in CSR-build passes
#define BCAP 8192         // fixed per-bucket capacity in tmp (mean fill ~2046)

__device__ inline u16 f2bf(float f) {
    union { float f; unsigned u; } v; v.f = f;
    unsigned r = v.u + 0x7fff + ((v.u >> 16) & 1);
    return (u16)(r >> 16);
}
__device__ inline float bflo(unsigned u) {
    union { unsigned u; float f; } v; v.u = u << 16; return v.f;
}
__device__ inline float bfhi(unsigned u) {
    union { unsigned u; float f; } v; v.u = u & 0xffff0000u; return v.f;
}
__device__ inline float bfs(u16 x) { return bflo((unsigned)x); }
__device__ inline unsigned pk(float lo, float hi) {
    return (unsigned)f2bf(lo) | ((unsigned)f2bf(hi) << 16);
}

// ---------------------------------------------------------------------------
// merged prep: zero bcur | pack W1 | pack W2 | cvt X->bf16
// Wp[((t*4+kk)*64+lane)*8+jj] = B[k][c], k = kk*32+(lane>>4)*8+jj, c = t*16+(lane&15)
// ---------------------------------------------------------------------------
__global__ __launch_bounds__(256) void prep_k(
    const float* __restrict__ X, u16* __restrict__ Xb, long n4,
    const float* __restrict__ W1, u16* __restrict__ Wp1,
    const float* __restrict__ W2, u16* __restrict__ Wp2,
    int* __restrict__ bcur, int nzero) {
    int b = blockIdx.x;
    int t = threadIdx.x;
    if (b < 4) {
        int i = b * 256 + t;
        if (i < nzero) bcur[i] = 0;
        return;
    }
    b -= 4;
    if (b < 192) {
        int i = b * 256 + t;   // 3*16384 entries
        int m = i >> 14, r = i & 16383;
        int jj = r & 7, lane = (r >> 3) & 63, kk = (r >> 9) & 3, tt = r >> 11;
        int k = kk * 32 + (lane >> 4) * 8 + jj;
        int c = tt * 16 + (lane & 15);
        Wp1[i] = f2bf(W1[(size_t)m * 16384 + k * 128 + c]);
        return;
    }
    b -= 192;
    if (b < 64) {
        int i = b * 256 + t;   // 16384 entries
        int jj = i & 7, lane = (i >> 3) & 63, kk = (i >> 9) & 3, tt = i >> 11;
        int k = kk * 32 + (lane >> 4) * 8 + jj;
        int c = tt * 16 + (lane & 15);
        float v = 0.f;
        if (c < 120) {
            int hop = c / 40, j = c - hop * 40;
            v = W2[(size_t)(hop * 128 + k) * 40 + j];
        }
        Wp2[i] = f2bf(v);
        return;
    }
    b -= 64;
    long i = (long)b * 256 + t;
    if (i >= n4) return;
    float4 v = ((const float4*)X)[i];
    ushort4 o;
    o.x = f2bf(v.x); o.y = f2bf(v.y); o.z = f2bf(v.z); o.w = f2bf(v.w);
    ((ushort4*)Xb)[i] = o;
}

// ---------------------------------------------------------------------------
// bucketed CSR build (bucket = 128 consecutive dst nodes, nb <= 1024).
// tmp: fixed-capacity bucket regions tmp[b*BCAP + r], packed (src<<7)|(dst&127).
// passB: block-local LDS histogram -> one global atomicAdd per (block,bucket)
// reserves a range -> LDS-cursor scatter. bcur accumulates per-bucket counts.
// ---------------------------------------------------------------------------
__global__ __launch_bounds__(256) void passB_k(
    const int* __restrict__ src, const int* __restrict__ dst,
    int* __restrict__ bcur, int* __restrict__ tmp, int E, int nbuck) {
    __shared__ int hist[1024];
    __shared__ int bbase[1024];
    int e0 = blockIdx.x * CSR_CHUNK;
    int e1 = min(e0 + CSR_CHUNK, E);
    for (int i = threadIdx.x; i < nbuck; i += 256) hist[i] = 0;
    __syncthreads();
    for (int e = e0 + threadIdx.x; e < e1; e += 256)
        atomicAdd(&hist[dst[e] >> 7], 1);
    __syncthreads();
    for (int i = threadIdx.x; i < nbuck; i += 256) {
        int c = hist[i];
        bbase[i] = c ? atomicAdd(&bcur[i], c) : 0;
        hist[i] = 0;
    }
    __syncthreads();
    for (int e = e0 + threadIdx.x; e < e1; e += 256) {
        int s = src[e], d = dst[e];
        int b = d >> 7;
        int r = atomicAdd(&hist[b], 1);
        tmp[b * BCAP + bbase[b] + r] = (s << 7) | (d & 127);
    }
}

// exclusive scan of bcur (per-bucket counts) -> bptr[nb+1]
__global__ void bscan_k(const int* __restrict__ bcur, int* __restrict__ bptr,
                        int nb, int E) {
    __shared__ int lds[256];
    int t = threadIdx.x;
    int base = t * 4;
    int v[4];
    int s = 0;
#pragma unroll
    for (int i = 0; i < 4; ++i) {
        v[i] = s;
        int idx = base + i;
        s += (idx < nb) ? bcur[idx] : 0;
    }
    int x = s;
    lds[t] = x;
    __syncthreads();
    for (int off = 1; off < 256; off <<= 1) {
        int y = (t >= off) ? lds[t - off] : 0;
        __syncthreads();
        x += y;
        lds[t] = x;
        __syncthreads();
    }
    int toff = x - s;
#pragma unroll
    for (int i = 0; i < 4; ++i) {
        int idx = base + i;
        if (idx < nb) bptr[idx] = toff + v[i];
    }
    if (t == 255) bptr[nb] = E;
}

__global__ __launch_bounds__(256) void passC_k(
    const int* __restrict__ tmp, const int* __restrict__ bptr,
    int* __restrict__ rowptr, float* __restrict__ norm, int* __restrict__ esrc,
    int N, int E) {
    __shared__ int cnt[128];
    __shared__ int sc[128];
    __shared__ int cur[128];
    int b = blockIdx.x, t = threadIdx.x;
    int base = bptr[b];
    int cnt_e = bptr[b + 1] - base;
    int tin = b * BCAP;
    int node0 = b << 7;
    int nNodes = min(128, N - node0);

    if (t < 128) cnt[t] = 0;
    __syncthreads();
    for (int i = t; i < cnt_e; i += 256)
        atomicAdd(&cnt[tmp[tin + i] & 127], 1);
    __syncthreads();
    if (t < 128) sc[t] = cnt[t];
    __syncthreads();
    for (int off = 1; off < 128; off <<= 1) {
        int y = 0;
        if (t < 128 && t >= off) y = sc[t - off];
        __syncthreads();
        if (t < 128) sc[t] += y;
        __syncthreads();
    }
    if (t < 128) {
        int ex = sc[t] - cnt[t];
        cur[t] = ex;
        if (t < nNodes) {
            rowptr[node0 + t] = base + ex;
            int d = cnt[t];
            norm[node0 + t] = (d > 0) ? rsqrtf((float)d) : 0.f;
        }
    }
    if (b == gridDim.x - 1 && t == 0) rowptr[N] = E;
    __syncthreads();
    for (int i = t; i < cnt_e; i += 256) {
        int p = tmp[tin + i];
        int pos = atomicAdd(&cur[p & 127], 1);
        esrc[base + pos] = p >> 7;
    }
}

// ---------------------------------------------------------------------------
// Tri-GEMM (layer 1): for m in {0,1,2}: dot_m = Xb @ Wp1[m].
//   m=0 -> P0b = dot (raw), m=1 -> P1b = dot (raw), m=2 -> g = norm*dot.
// A-fragments loaded once per stripe, B-fragments reloaded per (stripe, m).
// ---------------------------------------------------------------------------
__global__ __launch_bounds__(256, 2) void gemm3_k(
    const u16* __restrict__ Ab, const u16* __restrict__ Wp1,
    u16* __restrict__ P0b, u16* __restrict__ P1b, u16* __restrict__ g,
    const float* __restrict__ norm, int n, int nStripes) {
    int lane = threadIdx.x & 63;
    int wave = threadIdx.x >> 6;
    int rit = lane & 15;
    int kgrp = lane >> 4;

    for (int s = blockIdx.x; s < nStripes; s += gridDim.x) {
        int r0 = s * 64 + wave * 16;
        int ar = min(r0 + rit, n - 1);
        const bf16x8* arow = (const bf16x8*)(Ab + (size_t)ar * 128);
        bf16x8 afr[4];
#pragma unroll
        for (int kk = 0; kk < 4; ++kk) afr[kk] = arow[kk * 4 + kgrp];

        for (int m = 0; m < 3; ++m) {
            const bf16x8* wp = (const bf16x8*)(Wp1 + m * 16384);
            u16* outp = (m == 0) ? P0b : (m == 1) ? P1b : g;

            bf16x8 bfr[8][4];
#pragma unroll
            for (int t = 0; t < 8; ++t)
#pragma unroll
                for (int kk = 0; kk < 4; ++kk)
                    bfr[t][kk] = wp[(t * 4 + kk) * 64 + lane];

            f32x4 acc[8];
#pragma unroll
            for (int t = 0; t < 8; ++t) acc[t] = (f32x4)(0.f);
#pragma unroll
            for (int kk = 0; kk < 4; ++kk)
#pragma unroll
                for (int t = 0; t < 8; ++t)
                    acc[t] = __builtin_amdgcn_mfma_f32_16x16x32_bf16(
                        afr[kk], bfr[t][kk], acc[t], 0, 0, 0);

#pragma unroll
            for (int j = 0; j < 4; ++j) {
                int rs = r0 + kgrp * 4 + j;
                if (rs >= n) continue;
                float sc = (m == 2) ? norm[rs] : 1.f;
#pragma unroll
                for (int t = 0; t < 8; ++t) {
                    int c = t * 16 + rit;
                    outp[(size_t)rs * 128 + c] = f2bf(acc[t][j] * sc);
                }
            }
        }
    }
}

// ---------------------------------------------------------------------------
// Layer-2 GEMM: Z0 f32[N][40] | Z1 f32[N][40] | Z2b bf16[N][40] (*norm)
// ---------------------------------------------------------------------------
__global__ __launch_bounds__(256, 2) void gemm_l2_k(
    const u16* __restrict__ Ab, const u16* __restrict__ Wp,
    float* __restrict__ Z0, float* __restrict__ Z1, u16* __restrict__ Z2b,
    const float* __restrict__ norm, int n, int nStripes) {
    int lane = threadIdx.x & 63;
    int wave = threadIdx.x >> 6;
    int rit = lane & 15;
    int kgrp = lane >> 4;

    bf16x8 bfr[8][4];
    const bf16x8* wp = (const bf16x8*)Wp;
#pragma unroll
    for (int t = 0; t < 8; ++t)
#pragma unroll
        for (int kk = 0; kk < 4; ++kk)
            bfr[t][kk] = wp[(t * 4 + kk) * 64 + lane];

    for (int s = blockIdx.x; s < nStripes; s += gridDim.x) {
        int r0 = s * 64 + wave * 16;
        int ar = min(r0 + rit, n - 1);
        const bf16x8* arow = (const bf16x8*)(Ab + (size_t)ar * 128);
        bf16x8 afr[4];
#pragma unroll
        for (int kk = 0; kk < 4; ++kk) afr[kk] = arow[kk * 4 + kgrp];

        f32x4 acc[8];
#pragma unroll
        for (int t = 0; t < 8; ++t) acc[t] = (f32x4)(0.f);
#pragma unroll
        for (int kk = 0; kk < 4; ++kk)
#pragma unroll
            for (int t = 0; t < 8; ++t)
                acc[t] = __builtin_amdgcn_mfma_f32_16x16x32_bf16(
                    afr[kk], bfr[t][kk], acc[t], 0, 0, 0);

#pragma unroll
        for (int j = 0; j < 4; ++j) {
            int rs = r0 + kgrp * 4 + j;
            if (rs >= n) continue;
            float nr = norm[rs];
#pragma unroll
            for (int t = 0; t < 8; ++t) {
                int c = t * 16 + rit;
                float v = acc[t][j];
                if (c < 40) Z0[(size_t)rs * 40 + c] = v;
                else if (c < 80) Z1[(size_t)rs * 40 + c - 40] = v;
                else if (c < 120) Z2b[(size_t)rs * 40 + c - 80] = f2bf(v * nr);
            }
        }
    }
}

// ---------------------------------------------------------------------------
// Fused SpMM (d=128): a = sum_{e in in(n)} g[src(e),:]  (bf16 gather table)
// F=1: g2[n,:] = bf16( nn*(P[n,:] + nn*a) )
// F=2: h1[n,:] = bf16( relu(P[n,:] + nn*a + bias) )
// Wave per node: 4 edge slots x 16 lanes x uint4 (8 bf16 cols), 2x unroll.
// ---------------------------------------------------------------------------
template <int F>
__global__ __launch_bounds__(256) void spmm128_f_k(
    const u16* __restrict__ g, const u16* __restrict__ P,
    const float* __restrict__ bias, u16* __restrict__ outb,
    const float* __restrict__ norm,
    const int* __restrict__ rowptr, const int* __restrict__ esrc, int n) {
    int node = (blockIdx.x * 256 + threadIdx.x) >> 6;
    if (node >= n) return;
    int lane = threadIdx.x & 63;
    int sub = lane >> 4;
    int l16 = lane & 15;
    int beg = rowptr[node], end = rowptr[node + 1];
    float a[8];
#pragma unroll
    for (int j = 0; j < 8; ++j) a[j] = 0.f;

    int e = beg + sub;
    for (; e + 4 < end; e += 8) {
        int s0 = esrc[e], s1 = esrc[e + 4];
        uint4 v0 = *(const uint4*)(g + (size_t)s0 * 128 + l16 * 8);
        uint4 v1 = *(const uint4*)(g + (size_t)s1 * 128 + l16 * 8);
        a[0] += bflo(v0.x); a[1] += bfhi(v0.x);
        a[2] += bflo(v0.y); a[3] += bfhi(v0.y);
        a[4] += bflo(v0.z); a[5] += bfhi(v0.z);
        a[6] += bflo(v0.w); a[7] += bfhi(v0.w);
        a[0] += bflo(v1.x); a[1] += bfhi(v1.x);
        a[2] += bflo(v1.y); a[3] += bfhi(v1.y);
        a[4] += bflo(v1.z); a[5] += bfhi(v1.z);
        a[6] += bflo(v1.w); a[7] += bfhi(v1.w);
    }
    for (; e < end; e += 4) {
        int s = esrc[e];
        uint4 v = *(const uint4*)(g + (size_t)s * 128 + l16 * 8);
        a[0] += bflo(v.x); a[1] += bfhi(v.x);
        a[2] += bflo(v.y); a[3] += bfhi(v.y);
        a[4] += bflo(v.z); a[5] += bfhi(v.z);
        a[6] += bflo(v.w); a[7] += bfhi(v.w);
    }
#pragma unroll
    for (int j = 0; j < 8; ++j) {
        a[j] += __shfl_xor(a[j], 16);
        a[j] += __shfl_xor(a[j], 32);
    }
    if (sub == 0) {
        float nn = norm[node];
        uint4 pv = *(const uint4*)(P + (size_t)node * 128 + l16 * 8);
        float p[8];
        p[0] = bflo(pv.x); p[1] = bfhi(pv.x);
        p[2] = bflo(pv.y); p[3] = bfhi(pv.y);
        p[4] = bflo(pv.z); p[5] = bfhi(pv.z);
        p[6] = bflo(pv.w); p[7] = bfhi(pv.w);
        float r[8];
        if (F == 1) {
#pragma unroll
            for (int j = 0; j < 8; ++j) r[j] = nn * (p[j] + nn * a[j]);
        } else {
            float4 b0 = *(const float4*)(bias + l16 * 8);
            float4 b1v = *(const float4*)(bias + l16 * 8 + 4);
            r[0] = fmaxf(p[0] + nn * a[0] + b0.x, 0.f);
            r[1] = fmaxf(p[1] + nn * a[1] + b0.y, 0.f);
            r[2] = fmaxf(p[2] + nn * a[2] + b0.z, 0.f);
            r[3] = fmaxf(p[3] + nn * a[3] + b0.w, 0.f);
            r[4] = fmaxf(p[4] + nn * a[4] + b1v.x, 0.f);
            r[5] = fmaxf(p[5] + nn * a[5] + b1v.y, 0.f);
            r[6] = fmaxf(p[6] + nn * a[6] + b1v.z, 0.f);
            r[7] = fmaxf(p[7] + nn * a[7] + b1v.w, 0.f);
        }
        uint4 o;
        o.x = pk(r[0], r[1]);
        o.y = pk(r[2], r[3]);
        o.z = pk(r[4], r[5]);
        o.w = pk(r[6], r[7]);
        *(uint4*)(outb + (size_t)node * 128 + l16 * 8) = o;
    }
}

// u[n,j] = bf16( norm[n]*(Z1[n,j] + norm[n]*sum_e bf(Z2b[src(e),j])) ), j<40
__global__ __launch_bounds__(256) void spmm40_k(
    const u16* __restrict__ Z2b, const float* __restrict__ Z1, u16* __restrict__ u,
    const float* __restrict__ norm, const int* __restrict__ rowptr,
    const int* __restrict__ esrc, int n) {
    int gw = (blockIdx.x * 256 + threadIdx.x) >> 6;
    int lane = threadIdx.x & 63;
    if (gw >= n || lane >= 40) return;
    int beg = rowptr[gw], end = rowptr[gw + 1];
    float a = 0.f;
    int e = beg;
    for (; e + 3 < end; e += 4) {
        int s0 = esrc[e], s1 = esrc[e + 1], s2 = esrc[e + 2], s3 = esrc[e + 3];
        float v0 = bfs(Z2b[(size_t)s0 * 40 + lane]);
        float v1 = bfs(Z2b[(size_t)s1 * 40 + lane]);
        float v2 = bfs(Z2b[(size_t)s2 * 40 + lane]);
        float v3 = bfs(Z2b[(size_t)s3 * 40 + lane]);
        a += (v0 + v1) + (v2 + v3);
    }
    for (; e < end; ++e) a += bfs(Z2b[(size_t)esrc[e] * 40 + lane]);
    float nn = norm[gw];
    u[(size_t)gw * 40 + lane] = f2bf(nn * (Z1[(size_t)gw * 40 + lane] + nn * a));
}

// r = relu(Z0[n,:] + norm[n]*sum_e bf(u[src(e),:]) + b2); partial-sum for mean
__global__ __launch_bounds__(256) void spmm40_final_k(
    const u16* __restrict__ u, const float* __restrict__ Z0, const float* __restrict__ bias,
    float* __restrict__ partial, const float* __restrict__ norm,
    const int* __restrict__ rowptr, const int* __restrict__ esrc, int n, int nwaves) {
    __shared__ float lds[4][40];
    int wave = threadIdx.x >> 6;
    int lane = threadIdx.x & 63;
    int gw0 = blockIdx.x * 4 + wave;
    float accm = 0.f;
    float bb = (lane < 40) ? bias[lane] : 0.f;
    for (int node = gw0; node < n; node += nwaves) {
        if (lane < 40) {
            int beg = rowptr[node], end = rowptr[node + 1];
            float a = 0.f;
            int e = beg;
            for (; e + 3 < end; e += 4) {
                int s0 = esrc[e], s1 = esrc[e + 1], s2 = esrc[e + 2], s3 = esrc[e + 3];
                float v0 = bfs(u[(size_t)s0 * 40 + lane]);
                float v1 = bfs(u[(size_t)s1 * 40 + lane]);
                float v2 = bfs(u[(size_t)s2 * 40 + lane]);
                float v3 = bfs(u[(size_t)s3 * 40 + lane]);
                a += (v0 + v1) + (v2 + v3);
            }
            for (; e < end; ++e) a += bfs(u[(size_t)esrc[e] * 40 + lane]);
            float r = Z0[(size_t)node * 40 + lane] + norm[node] * a + bb;
            accm += fmaxf(r, 0.f);
        }
    }
    if (lane < 40) lds[wave][lane] = accm;
    __syncthreads();
    if (threadIdx.x < 40) {
        partial[blockIdx.x * 40 + threadIdx.x] =
            lds[0][threadIdx.x] + lds[1][threadIdx.x] + lds[2][threadIdx.x] + lds[3][threadIdx.x];
    }
}

__global__ __launch_bounds__(256) void reduce_mean_k(
    const float* __restrict__ partial, float* __restrict__ out, int nb, float invN) {
    __shared__ float lds[256];
    int c = blockIdx.x, t = threadIdx.x;
    float s = 0.f;
    for (int i = t; i < nb; i += 256) s += partial[(size_t)i * 40 + c];
    lds[t] = s;
    __syncthreads();
    for (int o = 128; o > 0; o >>= 1) {
        if (t < o) lds[t] += lds[t + o];
        __syncthreads();
    }
    if (t == 0) out[c] = lds[0] * invN;
}

extern "C" void kernel_launch(void* const* d_in, const int* in_sizes, int n_in,
                              void* d_out, int out_size, void* d_ws, size_t ws_size,
                              hipStream_t stream) {
    const float* X   = (const float*)d_in[0];
    const int*   src = (const int*)d_in[1];
    const int*   dst = (const int*)d_in[2];
    const float* W1  = (const float*)d_in[3];
    const float* b1  = (const float*)d_in[4];
    const float* W2  = (const float*)d_in[5];
    const float* b2  = (const float*)d_in[6];
    float* out = (float*)d_out;

    const int IN = 128;
    const int N = in_sizes[0] / IN;
    const int E = in_sizes[1];
    const int nb = (N + 127) >> 7;   // buckets of 128 nodes (<= 1024)

    char* w = (char*)d_ws;
    size_t off = 0;
    auto alloc = [&](size_t bytes) -> char* {
        char* p = w + off;
        off = (off + bytes + 15) & ~(size_t)15;
        return p;
    };
    float* norm    = (float*)alloc((size_t)N * 4);
    int*   rowptr  = (int*)alloc((size_t)(N + 1) * 4);
    int*   bptr    = (int*)alloc((size_t)(nb + 1) * 4);
    int*   bcur    = (int*)alloc((size_t)(nb + 1) * 4);
    int*   esrc    = (int*)alloc((size_t)E * 4);
    u16*   Xb      = (u16*)alloc((size_t)N * 128 * 2);
    u16*   h1b     = (u16*)alloc((size_t)N * 128 * 2);
    u16*   g       = (u16*)alloc((size_t)N * 128 * 2);
    u16*   g2      = (u16*)alloc((size_t)N * 128 * 2);
    u16*   Wp1     = (u16*)alloc(3 * 16384 * 2);
    u16*   Wp2     = (u16*)alloc(16384 * 2);
    float* bufF    = (float*)alloc((size_t)N * 128 * 4);  // tmp | P1b,P0b | Z
    u16*   ubuf    = (u16*)alloc((size_t)N * 40 * 2);
    float* partial = (float*)alloc(2048 * 40 * 4);

    int*   tmp = (int*)bufF;                         // CSR build only (nb*BCAP ints = 25.6 MB)
    u16*   P0b = (u16*)bufF;                         // [N][128] bf16 (layer-1)
    u16*   P1b = (u16*)bufF + (size_t)N * 128;       // [N][128] bf16 (layer-1)
    float* Z0  = bufF;                               // [N][40] f32 (layer-2)
    float* Z1  = bufF + (size_t)N * 40;
    u16*   Z2b = (u16*)(bufF + (size_t)2 * N * 40);

    int csr_blocks = (E + CSR_CHUNK - 1) / CSR_CHUNK;
    long n4 = (long)N * 128 / 4;
    int prep_grid = 4 + 192 + 64 + (int)((n4 + 255) / 256);

    // ---- prep (bcur zero + W packs + X cvt) ----
    prep_k<<<prep_grid, 256, 0, stream>>>(X, Xb, n4, W1, Wp1, W2, Wp2, bcur, nb);

    // ---- bucketed CSR build (fixed-cap tmp, LDS-aggregated atomics) ----
    passB_k<<<csr_blocks, 256, 0, stream>>>(src, dst, bcur, tmp, E, nb);
    bscan_k<<<1, 256, 0, stream>>>(bcur, bptr, nb, E);
    passC_k<<<nb, 256, 0, stream>>>(tmp, bptr, rowptr, norm, esrc, N, E);

    int nStripes = (N + 63) / 64;
    int gemm_grid = 512;
    int spmm_grid = (N + 3) / 4;

    // ---- layer 1: h1 = relu(XW0 + A(XW1 + A(XW2·n)) + b1), norm-folded ----
    gemm3_k<<<gemm_grid, 256, 0, stream>>>(
        Xb, Wp1, P0b, P1b, g, norm, N, nStripes);
    spmm128_f_k<1><<<spmm_grid, 256, 0, stream>>>(
        g, P1b, nullptr, g2, norm, rowptr, esrc, N);
    spmm128_f_k<2><<<spmm_grid, 256, 0, stream>>>(
        g2, P0b, b1, h1b, norm, rowptr, esrc, N);

    // ---- layer 2: out = mean(relu(Z0 + A(Z1 + A(Z2)) + b2)) ----
    gemm_l2_k<<<gemm_grid, 256, 0, stream>>>(
        h1b, Wp2, Z0, Z1, Z2b, norm, N, nStripes);
    spmm40_k<<<spmm_grid, 256, 0, stream>>>(Z2b, Z1, ubuf, norm, rowptr, esrc, N);
    spmm40_final_k<<<2048, 256, 0, stream>>>(ubuf, Z0, b2, partial, norm, rowptr, esrc, N, 8192);
    reduce_mean_k<<<40, 256, 0, stream>>>(partial, out, 2048, 1.f / (float)N);
}

// Round 14
// 416.777 us; speedup vs baseline: 1.2156x; 1.2156x over previous
//
#include <hip/hip_runtime.h>

typedef unsigned short u16;
typedef __attribute__((ext_vector_type(8))) short bf16x8;
typedef __attribute__((ext_vector_type(4))) float f32x4;

#define CSR_CHUNK 12288   // edges per block in CSR-build passes
#define BCAP 8192         // fixed per-bucket capacity in tmp (mean fill ~2046)

__device__ inline u16 f2bf(float f) {
    union { float f; unsigned u; } v; v.f = f;
    unsigned r = v.u + 0x7fff + ((v.u >> 16) & 1);
    return (u16)(r >> 16);
}
__device__ inline float bflo(unsigned u) {
    union { unsigned u; float f; } v; v.u = u << 16; return v.f;
}
__device__ inline float bfhi(unsigned u) {
    union { unsigned u; float f; } v; v.u = u & 0xffff0000u; return v.f;
}
__device__ inline float bfs(u16 x) { return bflo((unsigned)x); }
__device__ inline unsigned pk(float lo, float hi) {
    return (unsigned)f2bf(lo) | ((unsigned)f2bf(hi) << 16);
}

// ---------------------------------------------------------------------------
// merged prep: zero bcur | pack W1 | pack W2 | cvt X->bf16
// Wp[((t*4+kk)*64+lane)*8+jj] = B[k][c], k = kk*32+(lane>>4)*8+jj, c = t*16+(lane&15)
// ---------------------------------------------------------------------------
__global__ __launch_bounds__(256) void prep_k(
    const float* __restrict__ X, u16* __restrict__ Xb, long n4,
    const float* __restrict__ W1, u16* __restrict__ Wp1,
    const float* __restrict__ W2, u16* __restrict__ Wp2,
    int* __restrict__ bcur, int nzero) {
    int b = blockIdx.x;
    int t = threadIdx.x;
    if (b < 4) {
        int i = b * 256 + t;
        if (i < nzero) bcur[i] = 0;
        return;
    }
    b -= 4;
    if (b < 192) {
        int i = b * 256 + t;   // 3*16384 entries
        int m = i >> 14, r = i & 16383;
        int jj = r & 7, lane = (r >> 3) & 63, kk = (r >> 9) & 3, tt = r >> 11;
        int k = kk * 32 + (lane >> 4) * 8 + jj;
        int c = tt * 16 + (lane & 15);
        Wp1[i] = f2bf(W1[(size_t)m * 16384 + k * 128 + c]);
        return;
    }
    b -= 192;
    if (b < 64) {
        int i = b * 256 + t;   // 16384 entries
        int jj = i & 7, lane = (i >> 3) & 63, kk = (i >> 9) & 3, tt = i >> 11;
        int k = kk * 32 + (lane >> 4) * 8 + jj;
        int c = tt * 16 + (lane & 15);
        float v = 0.f;
        if (c < 120) {
            int hop = c / 40, j = c - hop * 40;
            v = W2[(size_t)(hop * 128 + k) * 40 + j];
        }
        Wp2[i] = f2bf(v);
        return;
    }
    b -= 64;
    long i = (long)b * 256 + t;
    if (i >= n4) return;
    float4 v = ((const float4*)X)[i];
    ushort4 o;
    o.x = f2bf(v.x); o.y = f2bf(v.y); o.z = f2bf(v.z); o.w = f2bf(v.w);
    ((ushort4*)Xb)[i] = o;
}

// ---------------------------------------------------------------------------
// bucketed CSR build (bucket = 128 consecutive dst nodes, nb <= 1024).
// tmp: fixed-capacity bucket regions tmp[b*BCAP + r], packed (src<<7)|(dst&127).
// passB: block-local LDS histogram -> one global atomicAdd per (block,bucket)
// reserves a range -> LDS-cursor scatter. bcur accumulates per-bucket counts.
// ---------------------------------------------------------------------------
__global__ __launch_bounds__(256) void passB_k(
    const int* __restrict__ src, const int* __restrict__ dst,
    int* __restrict__ bcur, int* __restrict__ tmp, int E, int nbuck) {
    __shared__ int hist[1024];
    __shared__ int bbase[1024];
    int e0 = blockIdx.x * CSR_CHUNK;
    int e1 = min(e0 + CSR_CHUNK, E);
    for (int i = threadIdx.x; i < nbuck; i += 256) hist[i] = 0;
    __syncthreads();
    for (int e = e0 + threadIdx.x; e < e1; e += 256)
        atomicAdd(&hist[dst[e] >> 7], 1);
    __syncthreads();
    for (int i = threadIdx.x; i < nbuck; i += 256) {
        int c = hist[i];
        bbase[i] = c ? atomicAdd(&bcur[i], c) : 0;
        hist[i] = 0;
    }
    __syncthreads();
    for (int e = e0 + threadIdx.x; e < e1; e += 256) {
        int s = src[e], d = dst[e];
        int b = d >> 7;
        int r = atomicAdd(&hist[b], 1);
        tmp[b * BCAP + bbase[b] + r] = (s << 7) | (d & 127);
    }
}

// exclusive scan of bcur (per-bucket counts) -> bptr[nb+1]
__global__ void bscan_k(const int* __restrict__ bcur, int* __restrict__ bptr,
                        int nb, int E) {
    __shared__ int lds[256];
    int t = threadIdx.x;
    int base = t * 4;
    int v[4];
    int s = 0;
#pragma unroll
    for (int i = 0; i < 4; ++i) {
        v[i] = s;
        int idx = base + i;
        s += (idx < nb) ? bcur[idx] : 0;
    }
    int x = s;
    lds[t] = x;
    __syncthreads();
    for (int off = 1; off < 256; off <<= 1) {
        int y = (t >= off) ? lds[t - off] : 0;
        __syncthreads();
        x += y;
        lds[t] = x;
        __syncthreads();
    }
    int toff = x - s;
#pragma unroll
    for (int i = 0; i < 4; ++i) {
        int idx = base + i;
        if (idx < nb) bptr[idx] = toff + v[i];
    }
    if (t == 255) bptr[nb] = E;
}

__global__ __launch_bounds__(256) void passC_k(
    const int* __restrict__ tmp, const int* __restrict__ bptr,
    int* __restrict__ rowptr, float* __restrict__ norm, int* __restrict__ esrc,
    int N, int E) {
    __shared__ int cnt[128];
    __shared__ int sc[128];
    __shared__ int cur[128];
    int b = blockIdx.x, t = threadIdx.x;
    int base = bptr[b];
    int cnt_e = bptr[b + 1] - base;
    int tin = b * BCAP;
    int node0 = b << 7;
    int nNodes = min(128, N - node0);

    if (t < 128) cnt[t] = 0;
    __syncthreads();
    for (int i = t; i < cnt_e; i += 256)
        atomicAdd(&cnt[tmp[tin + i] & 127], 1);
    __syncthreads();
    if (t < 128) sc[t] = cnt[t];
    __syncthreads();
    for (int off = 1; off < 128; off <<= 1) {
        int y = 0;
        if (t < 128 && t >= off) y = sc[t - off];
        __syncthreads();
        if (t < 128) sc[t] += y;
        __syncthreads();
    }
    if (t < 128) {
        int ex = sc[t] - cnt[t];
        cur[t] = ex;
        if (t < nNodes) {
            rowptr[node0 + t] = base + ex;
            int d = cnt[t];
            norm[node0 + t] = (d > 0) ? rsqrtf((float)d) : 0.f;
        }
    }
    if (b == gridDim.x - 1 && t == 0) rowptr[N] = E;
    __syncthreads();
    for (int i = t; i < cnt_e; i += 256) {
        int p = tmp[tin + i];
        int pos = atomicAdd(&cur[p & 127], 1);
        esrc[base + pos] = p >> 7;
    }
}

// ---------------------------------------------------------------------------
// MFMA GEMM: dot = A[n,128]b @ Wp.  (one B matrix per kernel -> no spill)
// MODE 1: Cb[n][128] bf16 = norm*dot
// MODE 4: Cb[n][128] bf16 = dot                (raw, for P0/P1 prefold)
// MODE 0: Z0 f32[N][40] | Z1 f32[N][40] | Z2b bf16[N][40] (*norm)
// ---------------------------------------------------------------------------
template <int MODE>
__global__ __launch_bounds__(256, 2) void gemm_mfma_k(
    const u16* __restrict__ Ab, const u16* __restrict__ Wp,
    float* __restrict__ Cf, u16* __restrict__ Cb,
    float* __restrict__ Cf2, u16* __restrict__ Cb2,
    const float* __restrict__ norm, int n, int nStripes) {
    int lane = threadIdx.x & 63;
    int wave = threadIdx.x >> 6;
    int rit = lane & 15;
    int kgrp = lane >> 4;

    bf16x8 bfr[8][4];
    const bf16x8* wp = (const bf16x8*)Wp;
#pragma unroll
    for (int t = 0; t < 8; ++t)
#pragma unroll
        for (int kk = 0; kk < 4; ++kk)
            bfr[t][kk] = wp[(t * 4 + kk) * 64 + lane];

    for (int s = blockIdx.x; s < nStripes; s += gridDim.x) {
        int r0 = s * 64 + wave * 16;
        int ar = min(r0 + rit, n - 1);
        const bf16x8* arow = (const bf16x8*)(Ab + (size_t)ar * 128);
        bf16x8 afr[4];
#pragma unroll
        for (int kk = 0; kk < 4; ++kk) afr[kk] = arow[kk * 4 + kgrp];

        f32x4 acc[8];
#pragma unroll
        for (int t = 0; t < 8; ++t) acc[t] = (f32x4)(0.f);
#pragma unroll
        for (int kk = 0; kk < 4; ++kk)
#pragma unroll
            for (int t = 0; t < 8; ++t)
                acc[t] = __builtin_amdgcn_mfma_f32_16x16x32_bf16(
                    afr[kk], bfr[t][kk], acc[t], 0, 0, 0);

#pragma unroll
        for (int j = 0; j < 4; ++j) {
            int rs = r0 + kgrp * 4 + j;
            if (rs >= n) continue;
            float nr = (MODE == 4) ? 0.f : norm[rs];
#pragma unroll
            for (int t = 0; t < 8; ++t) {
                int c = t * 16 + rit;
                float v = acc[t][j];
                if (MODE == 0) {
                    if (c < 40) Cf[(size_t)rs * 40 + c] = v;
                    else if (c < 80) Cf2[(size_t)rs * 40 + c - 40] = v;
                    else if (c < 120) Cb2[(size_t)rs * 40 + c - 80] = f2bf(v * nr);
                } else if (MODE == 1) {
                    Cb[(size_t)rs * 128 + c] = f2bf(v * nr);
                } else {  // MODE 4
                    Cb[(size_t)rs * 128 + c] = f2bf(v);
                }
            }
        }
    }
}

// ---------------------------------------------------------------------------
// Fused SpMM (d=128): a = sum_{e in in(n)} g[src(e),:]  (bf16 gather table)
// F=1: g2[n,:] = bf16( nn*(P[n,:] + nn*a) )
// F=2: h1[n,:] = bf16( relu(P[n,:] + nn*a + bias) )
// Wave per node: 4 edge slots x 16 lanes x uint4 (8 bf16 cols), 2x unroll.
// ---------------------------------------------------------------------------
template <int F>
__global__ __launch_bounds__(256) void spmm128_f_k(
    const u16* __restrict__ g, const u16* __restrict__ P,
    const float* __restrict__ bias, u16* __restrict__ outb,
    const float* __restrict__ norm,
    const int* __restrict__ rowptr, const int* __restrict__ esrc, int n) {
    int node = (blockIdx.x * 256 + threadIdx.x) >> 6;
    if (node >= n) return;
    int lane = threadIdx.x & 63;
    int sub = lane >> 4;
    int l16 = lane & 15;
    int beg = rowptr[node], end = rowptr[node + 1];
    float a[8];
#pragma unroll
    for (int j = 0; j < 8; ++j) a[j] = 0.f;

    int e = beg + sub;
    for (; e + 4 < end; e += 8) {
        int s0 = esrc[e], s1 = esrc[e + 4];
        uint4 v0 = *(const uint4*)(g + (size_t)s0 * 128 + l16 * 8);
        uint4 v1 = *(const uint4*)(g + (size_t)s1 * 128 + l16 * 8);
        a[0] += bflo(v0.x); a[1] += bfhi(v0.x);
        a[2] += bflo(v0.y); a[3] += bfhi(v0.y);
        a[4] += bflo(v0.z); a[5] += bfhi(v0.z);
        a[6] += bflo(v0.w); a[7] += bfhi(v0.w);
        a[0] += bflo(v1.x); a[1] += bfhi(v1.x);
        a[2] += bflo(v1.y); a[3] += bfhi(v1.y);
        a[4] += bflo(v1.z); a[5] += bfhi(v1.z);
        a[6] += bflo(v1.w); a[7] += bfhi(v1.w);
    }
    for (; e < end; e += 4) {
        int s = esrc[e];
        uint4 v = *(const uint4*)(g + (size_t)s * 128 + l16 * 8);
        a[0] += bflo(v.x); a[1] += bfhi(v.x);
        a[2] += bflo(v.y); a[3] += bfhi(v.y);
        a[4] += bflo(v.z); a[5] += bfhi(v.z);
        a[6] += bflo(v.w); a[7] += bfhi(v.w);
    }
#pragma unroll
    for (int j = 0; j < 8; ++j) {
        a[j] += __shfl_xor(a[j], 16);
        a[j] += __shfl_xor(a[j], 32);
    }
    if (sub == 0) {
        float nn = norm[node];
        uint4 pv = *(const uint4*)(P + (size_t)node * 128 + l16 * 8);
        float p[8];
        p[0] = bflo(pv.x); p[1] = bfhi(pv.x);
        p[2] = bflo(pv.y); p[3] = bfhi(pv.y);
        p[4] = bflo(pv.z); p[5] = bfhi(pv.z);
        p[6] = bflo(pv.w); p[7] = bfhi(pv.w);
        float r[8];
        if (F == 1) {
#pragma unroll
            for (int j = 0; j < 8; ++j) r[j] = nn * (p[j] + nn * a[j]);
        } else {
            float4 b0 = *(const float4*)(bias + l16 * 8);
            float4 b1v = *(const float4*)(bias + l16 * 8 + 4);
            r[0] = fmaxf(p[0] + nn * a[0] + b0.x, 0.f);
            r[1] = fmaxf(p[1] + nn * a[1] + b0.y, 0.f);
            r[2] = fmaxf(p[2] + nn * a[2] + b0.z, 0.f);
            r[3] = fmaxf(p[3] + nn * a[3] + b0.w, 0.f);
            r[4] = fmaxf(p[4] + nn * a[4] + b1v.x, 0.f);
            r[5] = fmaxf(p[5] + nn * a[5] + b1v.y, 0.f);
            r[6] = fmaxf(p[6] + nn * a[6] + b1v.z, 0.f);
            r[7] = fmaxf(p[7] + nn * a[7] + b1v.w, 0.f);
        }
        uint4 o;
        o.x = pk(r[0], r[1]);
        o.y = pk(r[2], r[3]);
        o.z = pk(r[4], r[5]);
        o.w = pk(r[6], r[7]);
        *(uint4*)(outb + (size_t)node * 128 + l16 * 8) = o;
    }
}

// u[n,j] = bf16( norm[n]*(Z1[n,j] + norm[n]*sum_e bf(Z2b[src(e),j])) ), j<40
__global__ __launch_bounds__(256) void spmm40_k(
    const u16* __restrict__ Z2b, const float* __restrict__ Z1, u16* __restrict__ u,
    const float* __restrict__ norm, const int* __restrict__ rowptr,
    const int* __restrict__ esrc, int n) {
    int gw = (blockIdx.x * 256 + threadIdx.x) >> 6;
    int lane = threadIdx.x & 63;
    if (gw >= n || lane >= 40) return;
    int beg = rowptr[gw], end = rowptr[gw + 1];
    float a = 0.f;
    int e = beg;
    for (; e + 3 < end; e += 4) {
        int s0 = esrc[e], s1 = esrc[e + 1], s2 = esrc[e + 2], s3 = esrc[e + 3];
        float v0 = bfs(Z2b[(size_t)s0 * 40 + lane]);
        float v1 = bfs(Z2b[(size_t)s1 * 40 + lane]);
        float v2 = bfs(Z2b[(size_t)s2 * 40 + lane]);
        float v3 = bfs(Z2b[(size_t)s3 * 40 + lane]);
        a += (v0 + v1) + (v2 + v3);
    }
    for (; e < end; ++e) a += bfs(Z2b[(size_t)esrc[e] * 40 + lane]);
    float nn = norm[gw];
    u[(size_t)gw * 40 + lane] = f2bf(nn * (Z1[(size_t)gw * 40 + lane] + nn * a));
}

// r = relu(Z0[n,:] + norm[n]*sum_e bf(u[src(e),:]) + b2); partial-sum for mean
__global__ __launch_bounds__(256) void spmm40_final_k(
    const u16* __restrict__ u, const float* __restrict__ Z0, const float* __restrict__ bias,
    float* __restrict__ partial, const float* __restrict__ norm,
    const int* __restrict__ rowptr, const int* __restrict__ esrc, int n, int nwaves) {
    __shared__ float lds[4][40];
    int wave = threadIdx.x >> 6;
    int lane = threadIdx.x & 63;
    int gw0 = blockIdx.x * 4 + wave;
    float accm = 0.f;
    float bb = (lane < 40) ? bias[lane] : 0.f;
    for (int node = gw0; node < n; node += nwaves) {
        if (lane < 40) {
            int beg = rowptr[node], end = rowptr[node + 1];
            float a = 0.f;
            int e = beg;
            for (; e + 3 < end; e += 4) {
                int s0 = esrc[e], s1 = esrc[e + 1], s2 = esrc[e + 2], s3 = esrc[e + 3];
                float v0 = bfs(u[(size_t)s0 * 40 + lane]);
                float v1 = bfs(u[(size_t)s1 * 40 + lane]);
                float v2 = bfs(u[(size_t)s2 * 40 + lane]);
                float v3 = bfs(u[(size_t)s3 * 40 + lane]);
                a += (v0 + v1) + (v2 + v3);
            }
            for (; e < end; ++e) a += bfs(u[(size_t)esrc[e] * 40 + lane]);
            float r = Z0[(size_t)node * 40 + lane] + norm[node] * a + bb;
            accm += fmaxf(r, 0.f);
        }
    }
    if (lane < 40) lds[wave][lane] = accm;
    __syncthreads();
    if (threadIdx.x < 40) {
        partial[blockIdx.x * 40 + threadIdx.x] =
            lds[0][threadIdx.x] + lds[1][threadIdx.x] + lds[2][threadIdx.x] + lds[3][threadIdx.x];
    }
}

__global__ __launch_bounds__(256) void reduce_mean_k(
    const float* __restrict__ partial, float* __restrict__ out, int nb, float invN) {
    __shared__ float lds[256];
    int c = blockIdx.x, t = threadIdx.x;
    float s = 0.f;
    for (int i = t; i < nb; i += 256) s += partial[(size_t)i * 40 + c];
    lds[t] = s;
    __syncthreads();
    for (int o = 128; o > 0; o >>= 1) {
        if (t < o) lds[t] += lds[t + o];
        __syncthreads();
    }
    if (t == 0) out[c] = lds[0] * invN;
}

extern "C" void kernel_launch(void* const* d_in, const int* in_sizes, int n_in,
                              void* d_out, int out_size, void* d_ws, size_t ws_size,
                              hipStream_t stream) {
    const float* X   = (const float*)d_in[0];
    const int*   src = (const int*)d_in[1];
    const int*   dst = (const int*)d_in[2];
    const float* W1  = (const float*)d_in[3];
    const float* b1  = (const float*)d_in[4];
    const float* W2  = (const float*)d_in[5];
    const float* b2  = (const float*)d_in[6];
    float* out = (float*)d_out;

    const int IN = 128;
    const int N = in_sizes[0] / IN;
    const int E = in_sizes[1];
    const int nb = (N + 127) >> 7;   // buckets of 128 nodes (<= 1024)

    char* w = (char*)d_ws;
    size_t off = 0;
    auto alloc = [&](size_t bytes) -> char* {
        char* p = w + off;
        off = (off + bytes + 15) & ~(size_t)15;
        return p;
    };
    float* norm    = (float*)alloc((size_t)N * 4);
    int*   rowptr  = (int*)alloc((size_t)(N + 1) * 4);
    int*   bptr    = (int*)alloc((size_t)(nb + 1) * 4);
    int*   bcur    = (int*)alloc((size_t)(nb + 1) * 4);
    int*   esrc    = (int*)alloc((size_t)E * 4);
    u16*   Xb      = (u16*)alloc((size_t)N * 128 * 2);
    u16*   h1b     = (u16*)alloc((size_t)N * 128 * 2);
    u16*   g       = (u16*)alloc((size_t)N * 128 * 2);
    u16*   g2      = (u16*)alloc((size_t)N * 128 * 2);
    u16*   Wp1     = (u16*)alloc(3 * 16384 * 2);
    u16*   Wp2     = (u16*)alloc(16384 * 2);
    float* bufF    = (float*)alloc((size_t)N * 128 * 4);  // tmp | P0b,P1b | Z
    u16*   ubuf    = (u16*)alloc((size_t)N * 40 * 2);
    float* partial = (float*)alloc(2048 * 40 * 4);

    int*   tmp = (int*)bufF;                         // CSR build only (nb*BCAP ints = 32 MB)
    u16*   P0b = (u16*)bufF;                         // [N][128] bf16 (layer-1)
    u16*   P1b = (u16*)bufF + (size_t)N * 128;       // [N][128] bf16 (layer-1)
    float* Z0  = bufF;                               // [N][40] f32 (layer-2)
    float* Z1  = bufF + (size_t)N * 40;
    u16*   Z2b = (u16*)(bufF + (size_t)2 * N * 40);

    int csr_blocks = (E + CSR_CHUNK - 1) / CSR_CHUNK;
    long n4 = (long)N * 128 / 4;
    int prep_grid = 4 + 192 + 64 + (int)((n4 + 255) / 256);

    // ---- prep (bcur zero + W packs + X cvt) ----
    prep_k<<<prep_grid, 256, 0, stream>>>(X, Xb, n4, W1, Wp1, W2, Wp2, bcur, nb);

    // ---- bucketed CSR build (fixed-cap tmp, LDS-aggregated atomics) ----
    passB_k<<<csr_blocks, 256, 0, stream>>>(src, dst, bcur, tmp, E, nb);
    bscan_k<<<1, 256, 0, stream>>>(bcur, bptr, nb, E);
    passC_k<<<nb, 256, 0, stream>>>(tmp, bptr, rowptr, norm, esrc, N, E);

    int nStripes = (N + 63) / 64;
    int gemm_grid = 512;
    int spmm_grid = (N + 3) / 4;

    // ---- layer 1: h1 = relu(XW0 + A(XW1 + A(XW2·n)) + b1), norm-folded ----
    gemm_mfma_k<1><<<gemm_grid, 256, 0, stream>>>(
        Xb, Wp1 + 2 * 16384, nullptr, g, nullptr, nullptr, norm, N, nStripes);
    gemm_mfma_k<4><<<gemm_grid, 256, 0, stream>>>(
        Xb, Wp1 + 1 * 16384, nullptr, P1b, nullptr, nullptr, norm, N, nStripes);
    gemm_mfma_k<4><<<gemm_grid, 256, 0, stream>>>(
        Xb, Wp1, nullptr, P0b, nullptr, nullptr, norm, N, nStripes);
    spmm128_f_k<1><<<spmm_grid, 256, 0, stream>>>(
        g, P1b, nullptr, g2, norm, rowptr, esrc, N);
    spmm128_f_k<2><<<spmm_grid, 256, 0, stream>>>(
        g2, P0b, b1, h1b, norm, rowptr, esrc, N);

    // ---- layer 2: out = mean(relu(Z0 + A(Z1 + A(Z2)) + b2)) ----
    gemm_mfma_k<0><<<gemm_grid, 256, 0, stream>>>(
        h1b, Wp2, Z0, nullptr, Z1, Z2b, norm, N, nStripes);
    spmm40_k<<<spmm_grid, 256, 0, stream>>>(Z2b, Z1, ubuf, norm, rowptr, esrc, N);
    spmm40_final_k<<<2048, 256, 0, stream>>>(ubuf, Z0, b2, partial, norm, rowptr, esrc, N, 8192);
    reduce_mean_k<<<40, 256, 0, stream>>>(partial, out, 2048, 1.f / (float)N);
}